// Round 1
// baseline (95.496 us; speedup 1.0000x reference)
//
#include <hip/hip_runtime.h>
#include <stdint.h>

// LearnedTripleConnect: B=8,N=8192,S=8,D=64. out[b,n] = mean_s( gelu([xi|xj|xk]W1+b1) ) W2 + b2
// Strategy: bf16 MFMA 16x16x32. GEMM1': H^T = W1^T * triple^T (gathered chunks are B-operand).
// mean-over-s BEFORE GEMM2 (linear): 8x less GEMM2 work.

#define NTOK   524288      // B*N*S
#define TPB_TILES 8        // tiles (64 tokens) per block
#define NBLK   1024        // 1024*8*64 = 524288 tokens

typedef short  short8 __attribute__((ext_vector_type(8)));
typedef float  f32x4  __attribute__((ext_vector_type(4)));

__device__ __forceinline__ unsigned short f2bf(float f){
  union { float f; unsigned u; } a; a.f = f;
  unsigned u = a.u;
  u += 0x7fffu + ((u >> 16) & 1u);   // RNE
  return (unsigned short)(u >> 16);
}
__device__ __forceinline__ unsigned pack2(float a, float b){
  return (unsigned)f2bf(a) | ((unsigned)f2bf(b) << 16);
}
__device__ __forceinline__ float fast_gelu(float x){
  // x * sigmoid(1.5957691*(x + 0.044715 x^3)) via exp2; |err vs exact gelu| ~3e-4
  float x2 = x * x;
  float t  = __builtin_fmaf(x2, -0.1029437f, -2.3022083f);
  float p  = __builtin_amdgcn_exp2f(x * t);
  return x * __builtin_amdgcn_rcpf(1.0f + p);
}

// ---------------- prep kernels ----------------
__global__ void cvt_x_kernel(const float* __restrict__ x, short* __restrict__ xb){
  long i = (long)blockIdx.x * blockDim.x + threadIdx.x;   // 0..524287, 8 elems each
  const float4* p = (const float4*)(x + i * 8);
  float4 a = p[0], b = p[1];
  short8 v;
  v[0]=(short)f2bf(a.x); v[1]=(short)f2bf(a.y); v[2]=(short)f2bf(a.z); v[3]=(short)f2bf(a.w);
  v[4]=(short)f2bf(b.x); v[5]=(short)f2bf(b.y); v[6]=(short)f2bf(b.z); v[7]=(short)f2bf(b.w);
  *(short8*)(xb + i * 8) = v;
}

// W1 frags: f = hw*24 + ks*4 + mt (hw:2, ks:6, mt:4). lane: rr=lane&15,gg=lane>>4
//   elem j: W1^T[h=64hw+16mt+rr][k=32ks+8gg+j]  = W1[k*128+h]
// W2 frags: f = w*4 + q. elem j: W2^T[d=16w+rr][k=32q+8gg+j] = W2[k*64+d]
__global__ void prep_w_kernel(const float* __restrict__ W1, const float* __restrict__ W2,
                              short* __restrict__ w1f, short* __restrict__ w2f){
  int t = threadIdx.x;
  for (int c = t; c < 48 * 64; c += 256){
    int lane = c & 63, f = c >> 6;
    int hw = f / 24, rem = f % 24, ks = rem >> 2, mt = rem & 3;
    int rr = lane & 15, gg = lane >> 4;
    int h = 64 * hw + 16 * mt + rr;
    short8 v;
    #pragma unroll
    for (int j = 0; j < 8; j++){
      int k = 32 * ks + 8 * gg + j;
      v[j] = (short)f2bf(W1[k * 128 + h]);
    }
    *(short8*)(w1f + (long)c * 8) = v;
  }
  for (int c = t; c < 16 * 64; c += 256){
    int lane = c & 63, f = c >> 6;
    int w = f >> 2, q = f & 3;
    int rr = lane & 15, gg = lane >> 4;
    int d = 16 * w + rr;
    short8 v;
    #pragma unroll
    for (int j = 0; j < 8; j++){
      int k = 32 * q + 8 * gg + j;
      v[j] = (short)f2bf(W2[k * 64 + d]);
    }
    *(short8*)(w2f + (long)c * 8) = v;
  }
}

// ---------------- main kernel ----------------
// stage one 64-token tile into chunk layout [kg 0..23][row 0..63] x 16B via global_load_lds.
__device__ __forceinline__ void stage_tile(short* buf, const short* xb, long tokbase,
                                           int jn, int kn, int wave, int lane){
  long token = tokbase + lane;
  int own = (int)(token >> 3);                 // b*8192+n
  int bb  = (int)((token >> 16) << 13);        // b*8192
  int jr = bb + jn, kr = bb + kn;
  #pragma unroll
  for (int q = 0; q < 6; q++){
    int kg  = wave + 4 * q;                    // waves cover 0..23
    int vec = kg >> 3, c8 = kg & 7;
    int src = (vec == 0) ? own : ((vec == 1) ? jr : kr);
    const short* gp = xb + (long)src * 64 + c8 * 8;
    __builtin_amdgcn_global_load_lds(
        (const __attribute__((address_space(1))) unsigned int*)gp,
        (__attribute__((address_space(3))) unsigned int*)(buf + kg * 512),
        16, 0, 0);
  }
}

__global__ __launch_bounds__(256, 2) void ltc_main(
    const short* __restrict__ xb,  const short* __restrict__ w1f,
    const short* __restrict__ w2f, const int* __restrict__ jidx,
    const int* __restrict__ kidx,  const float* __restrict__ b1,
    const float* __restrict__ b2,  float* __restrict__ out)
{
  __shared__ short    Ab[2][24 * 512];   // 48 KB double-buffered gather chunks
  __shared__ unsigned HBu[1024];         // 4 KB hbar chunks [kgh 0..15][slot 0..15] x 16B
  __shared__ float    Red[8][65];        // padded output staging
  __shared__ float    b1s[128];

  const int tid = threadIdx.x;
  const int wave = tid >> 6, lane = tid & 63;
  const int r = lane & 15, g = lane >> 4;
  const int hw = wave >> 1, tw = wave & 1;   // h-half / token-half roles

  if (tid < 128) b1s[tid] = b1[tid];

  int bid = blockIdx.x;
  int xcd = bid & 7, slot = bid >> 3;              // XCD x <-> batch x
  long tile0 = (long)(xcd * 128 + slot) * TPB_TILES;
  long tb64  = tile0 * 64;

  // resident weight fragments
  short8 w1frag[6][4];
  #pragma unroll
  for (int ks = 0; ks < 6; ks++)
    #pragma unroll
    for (int mt = 0; mt < 4; mt++)
      w1frag[ks][mt] = *(const short8*)(w1f + ((long)((hw * 24 + ks * 4 + mt) * 64 + lane)) * 8);
  short8 w2frag[4];
  #pragma unroll
  for (int q = 0; q < 4; q++)
    w2frag[q] = *(const short8*)(w2f + ((long)((wave * 4 + q) * 64 + lane)) * 8);

  float b2v[4];
  #pragma unroll
  for (int reg = 0; reg < 4; reg++) b2v[reg] = b2[16 * wave + 4 * g + reg];

  short* bufC = &Ab[0][0];
  short* bufN = &Ab[1][0];

  // prologue: idx + stage tile 0, preload idx for tile 1
  int jn = jidx[tb64 + lane], kn = kidx[tb64 + lane];
  stage_tile(bufC, xb, tb64, jn, kn, wave, lane);
  int jn1 = jidx[tb64 + 64 + lane], kn1 = kidx[tb64 + 64 + lane];

  for (int tt = 0; tt < TPB_TILES; ++tt){
    asm volatile("s_waitcnt vmcnt(0) lgkmcnt(0)\n\ts_barrier" ::: "memory");  // buf ready
    if (tt + 1 < TPB_TILES)
      stage_tile(bufN, xb, tb64 + (long)(tt + 1) * 64, jn1, kn1, wave, lane);
    if (tt + 2 < TPB_TILES){
      jn1 = jidx[tb64 + (long)(tt + 2) * 64 + lane];
      kn1 = kidx[tb64 + (long)(tt + 2) * 64 + lane];
    }

    // GEMM1': H^T = W1^T * triple^T, C-init = b1 broadcast
    f32x4 acc1[4][2];
    #pragma unroll
    for (int mt = 0; mt < 4; mt++){
      f32x4 binit = *(const f32x4*)&b1s[64 * hw + 16 * mt + 4 * g];
      acc1[mt][0] = binit; acc1[mt][1] = binit;
    }
    #pragma unroll
    for (int ks = 0; ks < 6; ks++){
      short8 bfr[2];
      #pragma unroll
      for (int ntl = 0; ntl < 2; ntl++)
        bfr[ntl] = *(const short8*)(bufC + ((4 * ks + g) * 64 + 32 * tw + 16 * ntl + r) * 8);
      #pragma unroll
      for (int mt = 0; mt < 4; mt++)
        #pragma unroll
        for (int ntl = 0; ntl < 2; ntl++)
          acc1[mt][ntl] = __builtin_amdgcn_mfma_f32_16x16x32_bf16(
              w1frag[ks][mt], bfr[ntl], acc1[mt][ntl], 0, 0, 0);
    }

    // GELU + mean-over-s partial (sum of 8 tokens) + pack to bf16
    unsigned P[4][2][2];
    #pragma unroll
    for (int mt = 0; mt < 4; mt++)
      #pragma unroll
      for (int ntl = 0; ntl < 2; ntl++){
        float z[4];
        #pragma unroll
        for (int reg = 0; reg < 4; reg++){
          float z0 = fast_gelu(acc1[mt][ntl][reg]);
          z0 += __shfl_xor(z0, 1);
          z0 += __shfl_xor(z0, 2);
          z0 += __shfl_xor(z0, 4);
          z[reg] = z0;
        }
        P[mt][ntl][0] = pack2(z[0], z[1]);
        P[mt][ntl][1] = pack2(z[2], z[3]);
      }

    // write hbar chunks (one writer lane per 8-lane group)
    if ((lane & 7) == 0){
      int half = r >> 3;
      #pragma unroll
      for (int mt = 0; mt < 4; mt++)
        #pragma unroll
        for (int ntl = 0; ntl < 2; ntl++){
          int kgh = 8 * hw + 2 * mt + (g >> 1);
          int sl  = 4 * tw + 2 * ntl + half;   // group index 0..7
          uint2 val; val.x = P[mt][ntl][0]; val.y = P[mt][ntl][1];
          *(uint2*)&HBu[(kgh * 16 + sl) * 4 + (g & 1) * 2] = val;
        }
    }
    asm volatile("s_waitcnt lgkmcnt(0)\n\ts_barrier" ::: "memory");  // HB published

    // GEMM2': O^T(64d x 8grp) per wave d-tile = wave
    f32x4 acc2 = {0.f, 0.f, 0.f, 0.f};
    #pragma unroll
    for (int q = 0; q < 4; q++){
      short8 hb = *(const short8*)&HBu[((4 * q + g) * 16 + r) * 4];
      acc2 = __builtin_amdgcn_mfma_f32_16x16x32_bf16(w2frag[q], hb, acc2, 0, 0, 0);
    }
    if (r < 8){
      #pragma unroll
      for (int reg = 0; reg < 4; reg++)
        Red[r][16 * wave + 4 * g + reg] = acc2[reg] * 0.125f + b2v[reg];
    }
    asm volatile("s_waitcnt lgkmcnt(0)\n\ts_barrier" ::: "memory");  // Red published

    long obase = (tile0 + tt) * 512;
    out[obase + tid]       = Red[tid >> 6][tid & 63];
    out[obase + tid + 256] = Red[(tid + 256) >> 6][(tid + 256) & 63];

    short* tmp = bufC; bufC = bufN; bufN = tmp;
  }
}

// ---------------- fallback (ws too small): correct, slow ----------------
__global__ void ltc_naive(const float* __restrict__ x, const int* __restrict__ jidx,
                          const int* __restrict__ kidx, const float* __restrict__ W1,
                          const float* __restrict__ b1, const float* __restrict__ W2,
                          const float* __restrict__ b2, float* __restrict__ out)
{
  int gidx = blockIdx.x;            // b*8192+n
  int b = gidx >> 13;
  __shared__ float trip[8][192];
  __shared__ float hb[128];
  int t = threadIdx.x;              // 128
  for (int i = t; i < 8 * 192; i += 128){
    int s = i / 192, c = i - s * 192;
    int v = c >> 6, cc = c & 63;
    int src;
    if (v == 0)      src = gidx & 8191;
    else if (v == 1) src = jidx[gidx * 8 + s];
    else             src = kidx[gidx * 8 + s];
    trip[s][c] = x[((long)(b << 13) + src) * 64 + cc];
  }
  __syncthreads();
  float z[8];
  #pragma unroll
  for (int s = 0; s < 8; s++) z[s] = b1[t];
  for (int k = 0; k < 192; k++){
    float w = W1[k * 128 + t];
    #pragma unroll
    for (int s = 0; s < 8; s++) z[s] = fmaf(trip[s][k], w, z[s]);
  }
  float acc = 0.f;
  #pragma unroll
  for (int s = 0; s < 8; s++) acc += fast_gelu(z[s]);
  hb[t] = acc * 0.125f;
  __syncthreads();
  if (t < 64){
    float o = b2[t];
    for (int h = 0; h < 128; h++) o = fmaf(hb[h], W2[h * 64 + t], o);
    out[(long)gidx * 64 + t] = o;
  }
}

extern "C" void kernel_launch(void* const* d_in, const int* in_sizes, int n_in,
                              void* d_out, int out_size, void* d_ws, size_t ws_size,
                              hipStream_t stream) {
  const float* x   = (const float*)d_in[0];
  const int*   jix = (const int*)  d_in[1];
  const int*   kix = (const int*)  d_in[2];
  const float* W1  = (const float*)d_in[3];
  const float* b1  = (const float*)d_in[4];
  const float* W2  = (const float*)d_in[5];
  const float* b2  = (const float*)d_in[6];
  float* out = (float*)d_out;

  const size_t xb_elems  = (size_t)8 * 8192 * 64;        // 4,194,304 bf16
  const size_t w1f_elems = 48 * 64 * 8;                  // 24,576
  const size_t w2f_elems = 16 * 64 * 8;                  // 8,192
  const size_t need = (xb_elems + w1f_elems + w2f_elems) * sizeof(short);

  if (ws_size >= need){
    short* xb  = (short*)d_ws;
    short* w1f = xb + xb_elems;
    short* w2f = w1f + w1f_elems;
    cvt_x_kernel<<<2048, 256, 0, stream>>>(x, xb);
    prep_w_kernel<<<1, 256, 0, stream>>>(W1, W2, w1f, w2f);
    ltc_main<<<NBLK, 256, 0, stream>>>(xb, w1f, w2f, jix, kix, b1, b2, out);
  } else {
    ltc_naive<<<8 * 8192, 128, 0, stream>>>(x, jix, kix, W1, b1, W2, b2, out);
  }
}

// Round 2
// 60.084 us; speedup vs baseline: 1.5894x; 1.5894x over previous
//
#include <hip/hip_runtime.h>
#include <stdint.h>

// LearnedTripleConnect: B=8,N=8192,S=8,D=64. out[b,n] = mean_s( gelu([xi|xj|xk]W1+b1) ) W2 + b2
// Round 2: tokens on MFMA row axis (32x32x16), s-reduce in registers (3 adds + 1 shfl),
// 8-wave blocks, 2 barriers/tile, 16 waves/CU.

#define NT   4            // 64-token tiles per block
#define NBLK 2048         // 2048*4*64 = 524288 tokens

typedef short  short8 __attribute__((ext_vector_type(8)));
typedef float  f32x4  __attribute__((ext_vector_type(4)));
typedef float  f32x16 __attribute__((ext_vector_type(16)));

__device__ __forceinline__ unsigned short f2bf(float f){
  union { float f; unsigned u; } a; a.f = f;
  unsigned u = a.u;
  u += 0x7fffu + ((u >> 16) & 1u);   // RNE
  return (unsigned short)(u >> 16);
}
__device__ __forceinline__ float fast_gelu(float x){
  // x * sigmoid(1.5957691*(x + 0.044715 x^3)) via exp2; |err vs exact gelu| ~3e-4
  float x2 = x * x;
  float t  = __builtin_fmaf(x2, -0.1029437f, -2.3022083f);
  float p  = __builtin_amdgcn_exp2f(x * t);
  return x * __builtin_amdgcn_rcpf(1.0f + p);
}

// ---------------- fused prep ----------------
// blocks 0..2047: x -> bf16 (xb). blocks 2048..2111: W1/W2 -> MFMA fragment layout.
// w1f: f = cb*12 + t. lane l, elem j: B-frag of W1 for 32x32x16:
//      B[k = 8*(l>>5)+j][col = l&31] of the (t,cb) 16x32 subtile -> W1[(t*16+8*(l>>5)+j)*128 + cb*32 + (l&31)]
// w2f: f = w*4 + q. lane l, elem j: B-frag of W2 for 16x16x32:
//      W2[(q*32 + 8*(l>>4)+j)*64 + w*16 + (l&15)]
__global__ void prep_kernel(const float* __restrict__ x, const float* __restrict__ W1,
                            const float* __restrict__ W2, short* __restrict__ xb,
                            short* __restrict__ w1f, short* __restrict__ w2f){
  int bid = blockIdx.x;
  if (bid < 2048){
    long i = (long)bid * 256 + threadIdx.x;   // 0..524287, 8 elems each
    const float4* p = (const float4*)(x + i * 8);
    float4 a = p[0], b = p[1];
    short8 v;
    v[0]=(short)f2bf(a.x); v[1]=(short)f2bf(a.y); v[2]=(short)f2bf(a.z); v[3]=(short)f2bf(a.w);
    v[4]=(short)f2bf(b.x); v[5]=(short)f2bf(b.y); v[6]=(short)f2bf(b.z); v[7]=(short)f2bf(b.w);
    *(short8*)(xb + i * 8) = v;
  } else if (threadIdx.x < 64){
    int f = bid - 2048, lane = threadIdx.x;
    short8 v;
    if (f < 48){
      int cb = f / 12, t = f % 12;
      #pragma unroll
      for (int j = 0; j < 8; j++)
        v[j] = (short)f2bf(W1[(t*16 + 8*(lane>>5) + j)*128 + cb*32 + (lane&31)]);
      *(short8*)(w1f + ((long)(f*64 + lane))*8) = v;
    } else {
      int g = f - 48; int w = g >> 2, q = g & 3;
      #pragma unroll
      for (int j = 0; j < 8; j++)
        v[j] = (short)f2bf(W2[(q*32 + 8*(lane>>4) + j)*64 + w*16 + (lane&15)]);
      *(short8*)(w2f + ((long)(g*64 + lane))*8) = v;
    }
  }
}

// ---------------- main kernel ----------------
// LDS A layout: 16B chunk (kg, tok) at byte (kg*64+tok)*16, kg = k8 index 0..23, tok 0..63.
// Staged linearly by global_load_lds (dest = base + lane*16, tok = lane).
__device__ __forceinline__ void stage_tile(short* buf, const short* xb, long tb,
                                           int jn, int kn, int w, int lane){
  long token = tb + lane;
  int own = (int)(token >> 3);                 // b*8192+n
  int bb  = (int)((token >> 16) << 13);        // b*8192
  int jr = bb + jn, kr = bb + kn;
  #pragma unroll
  for (int v = 0; v < 3; v++){
    int kg = w + 8 * v;                        // 8 waves cover kg 0..23, c8 = kg&7 = w
    int src = (v == 0) ? own : ((v == 1) ? jr : kr);
    const short* gp = xb + (long)src * 64 + w * 8;
    __builtin_amdgcn_global_load_lds(
        (const __attribute__((address_space(1))) unsigned int*)gp,
        (__attribute__((address_space(3))) unsigned int*)(buf + kg * 512),
        16, 0, 0);
  }
}

__global__ __launch_bounds__(512, 4) void ltc_main(
    const short* __restrict__ xb,  const short* __restrict__ w1f,
    const short* __restrict__ w2f, const int* __restrict__ jidx,
    const int* __restrict__ kidx,  const float* __restrict__ b1,
    const float* __restrict__ b2,  float* __restrict__ out)
{
  __shared__ short Ab[2][24 * 512];   // 48 KB double-buffered gather chunks
  __shared__ short HB[16 * 136];      // hbar: 8 valid rows x 128 h, stride 136 (16B-aligned, ~2-way banks)

  const int tid  = threadIdx.x;
  const int w    = tid >> 6, lane = tid & 63;
  const int cb   = w & 3,  rb  = w >> 2;      // h col-block / token row-block
  const int l31  = lane & 31, hi = lane >> 5;
  const int l15  = lane & 15, q4 = lane >> 4;

  // resident weight fragments
  short8 w1v[12];
  #pragma unroll
  for (int t = 0; t < 12; t++)
    w1v[t] = *(const short8*)(w1f + ((long)((cb * 12 + t) * 64 + lane)) * 8);
  short8 w2v[4];
  #pragma unroll
  for (int q = 0; q < 4; q++)
    w2v[q] = *(const short8*)(w2f + ((long)(((w & 3) * 4 + q) * 64 + lane)) * 8);

  float b1v = b1[cb * 32 + l31];
  float b2v = b2[(w & 3) * 16 + l15];

  // zero HB rows 8-15 (read by GEMM2 A-frags, results discarded; avoid NaN garbage)
  for (int i = tid; i < 8 * 136; i += 512) HB[8 * 136 + i] = 0;

  int bid  = blockIdx.x;
  int T0   = (bid & 7) * 1024 + (bid >> 3) * NT;   // batch-affine XCD swizzle
  long tb0 = (long)T0 * 64;

  int jn = jidx[tb0 + lane], kn = kidx[tb0 + lane];
  stage_tile(&Ab[0][0], xb, tb0, jn, kn, w, lane);
  int jn1 = 0, kn1 = 0;
  if (NT > 1){ jn1 = jidx[tb0 + 64 + lane]; kn1 = kidx[tb0 + 64 + lane]; }

  int cur = 0;
  for (int tt = 0; tt < NT; ++tt){
    asm volatile("s_waitcnt vmcnt(0)\n\ts_barrier" ::: "memory");  // Ab[cur] ready, HB consumed
    if (tt + 1 < NT)
      stage_tile(&Ab[cur ^ 1][0], xb, tb0 + (long)(tt + 1) * 64, jn1, kn1, w, lane);
    if (tt + 2 < NT){
      jn1 = jidx[tb0 + (long)(tt + 2) * 64 + lane];
      kn1 = kidx[tb0 + (long)(tt + 2) * 64 + lane];
    }

    // GEMM1: C[32 tok][32 h] = A(tok x K) * W1(K x h), C-init = b1
    const short* Ac = &Ab[cur][0];
    f32x16 acc;
    #pragma unroll
    for (int r = 0; r < 16; r++) acc[r] = b1v;
    #pragma unroll
    for (int t = 0; t < 12; t++){
      short8 afr = *(const short8*)(Ac + ((2 * t + hi) * 64 + rb * 32 + l31) * 8);
      acc = __builtin_amdgcn_mfma_f32_32x32x16_bf16(afr, w1v[t], acc, 0, 0, 0);
    }

    // GELU + s-reduce: row=(reg&3)+8*(reg>>2)+4*hi -> output o=reg>>2, s=(reg&3)+4*hi
    float hbv[4];
    #pragma unroll
    for (int o = 0; o < 4; o++){
      float s0 = fast_gelu(acc[4*o+0]);
      s0 += fast_gelu(acc[4*o+1]);
      s0 += fast_gelu(acc[4*o+2]);
      s0 += fast_gelu(acc[4*o+3]);
      float other = __shfl_xor(s0, 32);
      hbv[o] = (s0 + other) * 0.125f;
    }
    if (hi == 0){
      #pragma unroll
      for (int o = 0; o < 4; o++)
        HB[(rb * 4 + o) * 136 + cb * 32 + l31] = (short)f2bf(hbv[o]);
    }
    asm volatile("s_waitcnt lgkmcnt(0)\n\ts_barrier" ::: "memory");  // HB published

    // GEMM2 (waves 0-3): out[8 grp][64 d] = hbar(8x128) * W2(128x64)
    if (w < 4){
      f32x4 acc2 = {0.f, 0.f, 0.f, 0.f};
      #pragma unroll
      for (int q = 0; q < 4; q++){
        short8 hbf = *(const short8*)(HB + l15 * 136 + q * 32 + q4 * 8);
        acc2 = __builtin_amdgcn_mfma_f32_16x16x32_bf16(hbf, w2v[q], acc2, 0, 0, 0);
      }
      if (lane < 32){                       // rows 0-7 valid
        long G = ((long)(T0 + tt)) * 8;
        #pragma unroll
        for (int r = 0; r < 4; r++)
          out[(G + 4 * q4 + r) * 64 + (w & 3) * 16 + l15] = acc2[r] + b2v;
      }
    }
    cur ^= 1;
  }
}

// ---------------- fallback (ws too small): correct, slow ----------------
__global__ void ltc_naive(const float* __restrict__ x, const int* __restrict__ jidx,
                          const int* __restrict__ kidx, const float* __restrict__ W1,
                          const float* __restrict__ b1, const float* __restrict__ W2,
                          const float* __restrict__ b2, float* __restrict__ out)
{
  int gidx = blockIdx.x;            // b*8192+n
  int b = gidx >> 13;
  __shared__ float trip[8][192];
  __shared__ float hb[128];
  int t = threadIdx.x;              // 128
  for (int i = t; i < 8 * 192; i += 128){
    int s = i / 192, c = i - s * 192;
    int v = c >> 6, cc = c & 63;
    int src;
    if (v == 0)      src = gidx & 8191;
    else if (v == 1) src = jidx[gidx * 8 + s];
    else             src = kidx[gidx * 8 + s];
    trip[s][c] = x[((long)(b << 13) + src) * 64 + cc];
  }
  __syncthreads();
  float z[8];
  #pragma unroll
  for (int s = 0; s < 8; s++) z[s] = b1[t];
  for (int k = 0; k < 192; k++){
    float w = W1[k * 128 + t];
    #pragma unroll
    for (int s = 0; s < 8; s++) z[s] = fmaf(trip[s][k], w, z[s]);
  }
  float acc = 0.f;
  #pragma unroll
  for (int s = 0; s < 8; s++) acc += fast_gelu(z[s]);
  hb[t] = acc * 0.125f;
  __syncthreads();
  if (t < 64){
    float o = b2[t];
    for (int h = 0; h < 128; h++) o = fmaf(hb[h], W2[h * 64 + t], o);
    out[(long)gidx * 64 + t] = o;
  }
}

extern "C" void kernel_launch(void* const* d_in, const int* in_sizes, int n_in,
                              void* d_out, int out_size, void* d_ws, size_t ws_size,
                              hipStream_t stream) {
  const float* x   = (const float*)d_in[0];
  const int*   jix = (const int*)  d_in[1];
  const int*   kix = (const int*)  d_in[2];
  const float* W1  = (const float*)d_in[3];
  const float* b1  = (const float*)d_in[4];
  const float* W2  = (const float*)d_in[5];
  const float* b2  = (const float*)d_in[6];
  float* out = (float*)d_out;

  const size_t xb_elems  = (size_t)8 * 8192 * 64;        // 4,194,304 bf16
  const size_t w1f_elems = 48 * 64 * 8;
  const size_t w2f_elems = 16 * 64 * 8;
  const size_t need = (xb_elems + w1f_elems + w2f_elems) * sizeof(short);

  if (ws_size >= need){
    short* xb  = (short*)d_ws;
    short* w1f = xb + xb_elems;
    short* w2f = w1f + w1f_elems;
    prep_kernel<<<2112, 256, 0, stream>>>(x, W1, W2, xb, w1f, w2f);
    ltc_main<<<NBLK, 512, 0, stream>>>(xb, w1f, w2f, jix, kix, b1, b2, out);
  } else {
    ltc_naive<<<8 * 8192, 128, 0, stream>>>(x, jix, kix, W1, b1, W2, b2, out);
  }
}